// Round 6
// baseline (304.957 us; speedup 1.0000x reference)
//
#include <hip/hip_runtime.h>
#include <math.h>

#define NUM_HEADS   16
#define HEAD_DIM    64
#define KMAXN       64
#define LOCAL_WIN   512
#define LOG_N       17
#define LEAF_START  131072
#define MAX_LEN_TOK 65536
#define ROW         1024      // NUM_HEADS*HEAD_DIM floats per token
#define SLICE       65536     // 64 tokens * ROW floats per partial slice
#define MAXN        34

typedef float vf4 __attribute__((ext_vector_type(4)));

__device__ __forceinline__ vf4 ntload(const float* p) {
    return __builtin_nontemporal_load((const vf4*)p);
}

// ---------------------------------------------------------------------------
// 256-thread (4-wave) per-(node,head) attention tile: reduce CB strided
// slices (stride SLICE floats) into LDS f-slice, then attention.
// Verified numerics (round-0/round-3, absmax 0.0).
// ---------------------------------------------------------------------------
__device__ __forceinline__ void attn_tile256(const float* __restrict__ bp, int CB, float invC,
                                             int K, int dep, int h,
                                             const float* __restrict__ q,
                                             const float* __restrict__ W,
                                             const float* __restrict__ temp,
                                             float* __restrict__ node_out_row,
                                             float (&fh)[64][64], float* qs, float* qds,
                                             float* sv, float* ps, float (&red)[4][64]) {
    int tid = threadIdx.x, lane = tid & 63, w = tid >> 6;
    if (tid < 64) qs[tid] = q[h * 64 + tid];
    // 64 rows x 16 float4-cols = 1024 items; 4 per thread
    for (int id = tid; id < 1024; id += 256) {
        int r = id >> 4, c4 = (id & 15) << 2;
        if (r < K) {
            vf4 s0 = 0.f, s1 = 0.f, s2 = 0.f, s3 = 0.f;
            const float* p = bp + (long)r * ROW + c4;
            int cb = 0;
            for (; cb + 4 <= CB; cb += 4) {
                s0 += *(const vf4*)(p + (long)cb * SLICE);
                s1 += *(const vf4*)(p + (long)(cb + 1) * SLICE);
                s2 += *(const vf4*)(p + (long)(cb + 2) * SLICE);
                s3 += *(const vf4*)(p + (long)(cb + 3) * SLICE);
            }
            for (; cb < CB; ++cb) s0 += *(const vf4*)(p + (long)cb * SLICE);
            s0 += s1; s2 += s3; s0 += s2;
            s0 *= invC;
            *(vf4*)&fh[r][c4] = s0;
        }
    }
    __syncthreads();

    // q_depth = q + q @ W[dep]^T
    float qp = 0.f;
    const float* Wr = W + ((long)dep * 64 + lane) * 64;
    #pragma unroll
    for (int e = w * 16; e < w * 16 + 16; ++e) qp += qs[e] * Wr[e];
    red[w][lane] = qp;
    __syncthreads();
    if (w == 0) qds[lane] = qs[lane] + red[0][lane] + red[1][lane] + red[2][lane] + red[3][lane];
    __syncthreads();
    float qd    = qds[lane];
    float sp    = log1pf(expf(temp[dep]));
    float scale = 1.0f / ((sp + 1e-6f) * 8.0f);

    for (int k = w; k < K; k += 4) {
        float p2 = qd * fh[k][lane];
        #pragma unroll
        for (int m = 1; m < 64; m <<= 1) p2 += __shfl_xor(p2, m, 64);
        if (lane == 0) sv[k] = p2 * scale;
    }
    __syncthreads();

    if (w == 0) {
        float s  = (lane < K) ? sv[lane] : -1e30f;
        float mx = s;
        #pragma unroll
        for (int m = 1; m < 64; m <<= 1) mx = fmaxf(mx, __shfl_xor(mx, m, 64));
        float e = (lane < K) ? expf(s - mx) : 0.f;
        float S = e;
        #pragma unroll
        for (int m = 1; m < 64; m <<= 1) S += __shfl_xor(S, m, 64);
        ps[lane] = e / S;
    }
    __syncthreads();

    float o = 0.f;
    for (int k = w; k < K; k += 4) o += ps[k] * fh[k][lane];
    red[w][lane] = o;
    __syncthreads();
    if (w == 0)
        node_out_row[lane] = red[0][lane] + red[1][lane] + red[2][lane] + red[3][lane];
}

// ---------------------------------------------------------------------------
// KA: [0, bbK1)        -> K1 partial-sum units (C>1 nodes, 2-row k-groups,
//                         cb-major, cpb=32; round-5 verified streaming loop)
//     [bbK1, bbK1+16)  -> local-window attention, one head per block
//                         (round-3 verified 256-thread 2-token/thread path)
//     [bbK1+16, ...)   -> direct (C==1) node tiles, straight from v
// All three classes are mutually independent; the light attention blocks
// ride in the streaming phase's bandwidth shadow. Grid (<=~900) stays below
// full-residency capacity at 4 blocks/CU -> no dispatch tail. No fences.
// ---------------------------------------------------------------------------
struct KAArgs {
    int nPart, bbK1, nDirect, pos;
    int offLocal, offNodeOut;
    int a1[MAXN], cpb1[MAXN], C1[MAXN], off1[MAXN], bbase[MAXN];
    int aD[MAXN], KD[MAXN], depD[MAXN], idxD[MAXN];
};

__global__ __launch_bounds__(256, 4) void kA(const float* __restrict__ v,
                                             const float* __restrict__ q,
                                             const float* __restrict__ W,
                                             const float* __restrict__ temp,
                                             float* __restrict__ ws, KAArgs A) {
    __shared__ float fh[64][64];
    __shared__ float qs[64], qds[64], sv[64], ps[64];
    __shared__ float red[4][64];
    __shared__ float sc[LOCAL_WIN];
    __shared__ float wred[8];
    __shared__ float mS[2];

    int b = blockIdx.x, tid = threadIdx.x;
    int lane = tid & 63, w = tid >> 6;

    if (b < A.bbK1) {
        // ---- K1 streaming partial unit (round-5 verified; K=64 always) ----
        int node = 0;
        for (int i = 1; i < A.nPart; ++i) if (b >= A.bbase[i]) node = i;
        int lb = b - A.bbase[node];
        int cb = lb >> 5;                  // cb-major, 32 k-groups per cb
        int kg = lb & 31;
        int k0 = kg * 2;                   // 2 rows per group
        int c0 = cb * A.cpb1[node];
        int c1 = c0 + A.cpb1[node];
        if (c1 > A.C1[node]) c1 = A.C1[node];
        int a  = A.a1[node];
        int j4 = tid * 4;

        vf4 acc0 = 0.f, acc1 = 0.f;
        int c = c0;
        for (; c + 4 <= c1; c += 4) {
            const float* p0 = v + (long)(a + c * 64 + k0) * ROW + j4;
            vf4 y0 = ntload(p0);
            vf4 y1 = ntload(p0 + ROW);
            vf4 y2 = ntload(p0 + SLICE);
            vf4 y3 = ntload(p0 + SLICE + ROW);
            vf4 y4 = ntload(p0 + 2 * SLICE);
            vf4 y5 = ntload(p0 + 2 * SLICE + ROW);
            vf4 y6 = ntload(p0 + 3 * SLICE);
            vf4 y7 = ntload(p0 + 3 * SLICE + ROW);
            acc0 += y0 + y2 + y4 + y6;
            acc1 += y1 + y3 + y5 + y7;
        }
        for (; c < c1; ++c) {
            const float* p0 = v + (long)(a + c * 64 + k0) * ROW + j4;
            acc0 += ntload(p0);
            acc1 += ntload(p0 + ROW);
        }
        float* wp = ws + (long)A.off1[node] + (long)cb * SLICE + (long)k0 * ROW + j4;
        *(vf4*)(wp)       = acc0;
        *(vf4*)(wp + ROW) = acc1;
    } else if (b < A.bbK1 + NUM_HEADS) {
        // ---- local-window attention, head h, 2 tokens/thread (verified) ----
        int h    = b - A.bbK1;
        int nloc = A.pos < LOCAL_WIN ? A.pos : LOCAL_WIN;
        int t0   = A.pos - nloc;

        if (tid < 64) qs[tid] = q[h * 64 + tid];
        __syncthreads();

        float s0 = -1e30f, s1 = -1e30f;
        if (tid < nloc) {
            const float* vr = v + (long)(t0 + tid) * ROW + h * 64;
            float acc = 0.f;
            #pragma unroll 8
            for (int d = 0; d < 64; ++d) acc += qs[d] * vr[d];
            s0 = acc * 0.125f;
        }
        if (tid + 256 < nloc) {
            const float* vr = v + (long)(t0 + tid + 256) * ROW + h * 64;
            float acc = 0.f;
            #pragma unroll 8
            for (int d = 0; d < 64; ++d) acc += qs[d] * vr[d];
            s1 = acc * 0.125f;
        }
        float mx = fmaxf(s0, s1);
        #pragma unroll
        for (int m = 1; m < 64; m <<= 1) mx = fmaxf(mx, __shfl_xor(mx, m, 64));
        if (lane == 0) wred[w] = mx;
        __syncthreads();
        if (tid == 0) {
            float m2 = wred[0];
            for (int i = 1; i < 4; ++i) m2 = fmaxf(m2, wred[i]);
            mS[0] = m2;
        }
        __syncthreads();
        float m = mS[0];

        float e0 = (tid < nloc)       ? expf(s0 - m) : 0.f;
        float e1 = (tid + 256 < nloc) ? expf(s1 - m) : 0.f;
        sc[tid]       = e0;
        sc[tid + 256] = e1;
        float su = e0 + e1;
        #pragma unroll
        for (int mm = 1; mm < 64; mm <<= 1) su += __shfl_xor(su, mm, 64);
        if (lane == 0) wred[4 + w] = su;
        __syncthreads();
        if (tid == 0) {
            float S2 = 0.f;
            for (int i = 0; i < 4; ++i) S2 += wred[4 + i];
            mS[1] = S2;
        }
        __syncthreads();
        float S = mS[1];

        // lane = d; wave w handles tokens [w*128, w*128+128)
        float acc = 0.f;
        {
            const float* vb = v + (long)t0 * ROW + h * 64 + lane;
            int tb = w * 128;
            #pragma unroll 4
            for (int i = 0; i < 128; ++i) {
                int t = tb + i;
                if (t < nloc) acc += sc[t] * vb[(long)t * ROW];
            }
        }
        red[w][lane] = acc;
        __syncthreads();
        if (w == 0) {
            float tot = red[0][lane] + red[1][lane] + red[2][lane] + red[3][lane];
            (ws + A.offLocal)[h * 64 + lane] = (nloc > 0) ? tot / S : 0.f;
        }
    } else {
        // ---- direct small-node tile (C==1), reads v, no K1 dependency ----
        int t = b - A.bbK1 - NUM_HEADS;
        int d = t >> 4, h = t & 15;
        attn_tile256(v + (long)A.aD[d] * ROW + h * 64, 1, 1.0f,
                     A.KD[d], A.depD[d], h, q, W, temp,
                     ws + A.offNodeOut + (long)A.idxD[d] * ROW + h * 64,
                     fh, qs, qds, sv, ps, red);
    }
}

// ---------------------------------------------------------------------------
// KB: big-node (C>1) tiles only: per-(node,head) blocks finalize the
// CB-reduction for THEIR head slice (16 head blocks partition ROW -> each
// partial slice read exactly once in aggregate), then attention from LDS.
// 512 threads = 8 waves (round-5 verified numerics).
// ---------------------------------------------------------------------------
struct KBArgs {
    int nBig;
    int C1[MAXN], CB1[MAXN], off1[MAXN], dep1[MAXN], idx1[MAXN];
};

__global__ __launch_bounds__(512) void kB(const float* __restrict__ ws,
                                          const float* __restrict__ q,
                                          const float* __restrict__ W,
                                          const float* __restrict__ temp,
                                          float* __restrict__ node_out, KBArgs B) {
    int h   = blockIdx.x;
    int p   = blockIdx.y;
    int tid = threadIdx.x;
    int lane = tid & 63;
    int w    = tid >> 6;                   // wave 0..7

    __shared__ float fh[64][64];
    __shared__ float qs[64], qds[64], sv[64], ps[64];
    __shared__ float red[8][64];

    if (tid < 64) qs[tid] = q[h * 64 + tid];

    const float* bp = ws + (long)B.off1[p] + h * 64;
    int   CB   = B.CB1[p];
    float invC = 1.0f / (float)B.C1[p];

    // 64 rows x 16 float4-cols = 1024 (r,c4) pairs; 2 per thread.
    for (int id = tid; id < 1024; id += 512) {
        int r  = id >> 4;
        int c4 = (id & 15) << 2;
        vf4 s0 = 0.f, s1 = 0.f, s2 = 0.f, s3 = 0.f;
        const float* pp = bp + (long)r * ROW + c4;
        int cb = 0;
        for (; cb + 4 <= CB; cb += 4) {
            s0 += *(const vf4*)(pp + (long)cb * SLICE);
            s1 += *(const vf4*)(pp + (long)(cb + 1) * SLICE);
            s2 += *(const vf4*)(pp + (long)(cb + 2) * SLICE);
            s3 += *(const vf4*)(pp + (long)(cb + 3) * SLICE);
        }
        for (; cb < CB; ++cb) s0 += *(const vf4*)(pp + (long)cb * SLICE);
        s0 += s1; s2 += s3; s0 += s2;
        s0 *= invC;
        *(vf4*)&fh[r][c4] = s0;
    }
    __syncthreads();

    // q_depth = q + q @ W[dep]^T ; 8 waves x 8 elems each
    int dep = B.dep1[p];
    float qp = 0.f;
    const float* Wr = W + ((long)dep * 64 + lane) * 64;
    #pragma unroll
    for (int e = w * 8; e < w * 8 + 8; ++e) qp += qs[e] * Wr[e];
    red[w][lane] = qp;
    __syncthreads();
    if (w == 0) {
        float t = qs[lane];
        #pragma unroll
        for (int i = 0; i < 8; ++i) t += red[i][lane];
        qds[lane] = t;
    }
    __syncthreads();
    float qd    = qds[lane];
    float sp    = log1pf(expf(temp[dep]));
    float scale = 1.0f / ((sp + 1e-6f) * 8.0f);

    for (int k = w; k < 64; k += 8) {
        float p2 = qd * fh[k][lane];
        #pragma unroll
        for (int m = 1; m < 64; m <<= 1) p2 += __shfl_xor(p2, m, 64);
        if (lane == 0) sv[k] = p2 * scale;
    }
    __syncthreads();

    if (w == 0) {
        float s  = sv[lane];
        float mx = s;
        #pragma unroll
        for (int m = 1; m < 64; m <<= 1) mx = fmaxf(mx, __shfl_xor(mx, m, 64));
        float e = expf(s - mx);
        float S = e;
        #pragma unroll
        for (int m = 1; m < 64; m <<= 1) S += __shfl_xor(S, m, 64);
        ps[lane] = e / S;
    }
    __syncthreads();

    float o = 0.f;
    for (int k = w; k < 64; k += 8) o += ps[k] * fh[k][lane];
    red[w][lane] = o;
    __syncthreads();
    if (w == 0) {
        float t = 0.f;
        #pragma unroll
        for (int i = 0; i < 8; ++i) t += red[i][lane];
        node_out[(long)B.idx1[p] * ROW + h * 64 + lane] = t;
    }
}

// ---------------- K3: trivial combine: out = local + mean(node_out)
__global__ __launch_bounds__(256) void k3_combine(const float* __restrict__ node_out,
                                                  const float* __restrict__ local_out,
                                                  int nNodes,
                                                  float* __restrict__ out) {
    int i = blockIdx.x * 256 + threadIdx.x;    // 0..1023 = h*64+d
    float tr = 0.f;
    for (int n = 0; n < nNodes; ++n) tr += node_out[(long)n * ROW + i];
    if (nNodes > 0) tr /= (float)nNodes;
    out[i] = local_out[i] + tr;
}

static int floor_log2_host(unsigned x) { int r = 0; while (x >>= 1) ++r; return r; }

extern "C" void kernel_launch(void* const* d_in, const int* in_sizes, int n_in,
                              void* d_out, int out_size, void* d_ws, size_t ws_size,
                              hipStream_t stream) {
    const float* v    = (const float*)d_in[0];
    const float* q    = (const float*)d_in[1];
    const float* W    = (const float*)d_in[2];
    const float* temp = (const float*)d_in[3];
    float* out        = (float*)d_out;
    float* ws         = (float*)d_ws;

    int pos = in_sizes[0] / ROW;

    int n_nodes = 0;
    int nv[MAXN], nd[MAXN];
    if (pos > 0) {
        long l = LEAF_START;
        long r = LEAF_START + (pos < MAX_LEN_TOK ? pos : MAX_LEN_TOK);
        while (l < r) {
            if (l & 1) { nv[n_nodes] = (int)l; nd[n_nodes] = LOG_N - floor_log2_host((unsigned)l); ++n_nodes; ++l; }
            if (r & 1) { --r; nv[n_nodes] = (int)r; nd[n_nodes] = LOG_N - floor_log2_host((unsigned)r); ++n_nodes; }
            l >>= 1; r >>= 1;
        }
    }

    // cpb: smallest in {32,...} whose partial slices fit ws.
    // ws layout: partials | node_out [n_nodes*ROW] | local_out [ROW]
    int cpb_choice = 1024;
    for (int cand : {32, 64, 128, 256, 512, 1024}) {
        long tot_cb = 0;
        for (int i = 0; i < n_nodes; ++i) {
            int L = 1 << nd[i];
            int C = (L > KMAXN) ? L / KMAXN : 1;
            if (C > 1) tot_cb += (C + cand - 1) / cand;
        }
        long need = (tot_cb * (long)SLICE + (long)n_nodes * ROW + ROW) * 4;
        if (need <= (long)ws_size) { cpb_choice = cand; break; }
    }

    KAArgs A{}; KBArgs B{};
    A.pos = pos;
    int off = 0, bb = 0, nBig = 0, nDirect = 0;
    for (int i = 0; i < n_nodes; ++i) {
        int depth = nd[i];
        int L = 1 << depth;
        int a = (nv[i] << depth) - LEAF_START;
        int K = (L < KMAXN) ? L : KMAXN;
        int C = (L > KMAXN) ? L / KMAXN : 1;
        if (C > 1) {
            int CB  = (C + cpb_choice - 1) / cpb_choice;
            int cpb = (C + CB - 1) / CB;
            A.a1[nBig] = a; A.cpb1[nBig] = cpb; A.C1[nBig] = C;
            A.off1[nBig] = off; A.bbase[nBig] = bb;
            B.C1[nBig] = C; B.CB1[nBig] = CB; B.off1[nBig] = off;
            B.dep1[nBig] = depth; B.idx1[nBig] = i;
            off += CB * SLICE;
            bb  += 32 * CB;            // 2 k-rows per block (32 kg), cb-major
            ++nBig;
        } else {
            A.aD[nDirect] = a; A.KD[nDirect] = K;
            A.depD[nDirect] = depth; A.idxD[nDirect] = i;
            ++nDirect;
        }
    }
    A.nPart = nBig; A.bbK1 = bb; A.nDirect = nDirect;
    B.nBig = nBig;
    A.offNodeOut = off;
    A.offLocal   = off + n_nodes * ROW;

    float* node_outp  = ws + (long)A.offNodeOut;           // n_nodes * ROW
    float* local_outp = ws + (long)A.offLocal;             // ROW

    int gridA = bb + NUM_HEADS + nDirect * NUM_HEADS;
    hipLaunchKernelGGL(kA, dim3(gridA), dim3(256), 0, stream, v, q, W, temp, ws, A);

    if (nBig > 0)
        hipLaunchKernelGGL(kB, dim3(NUM_HEADS, nBig), dim3(512), 0, stream,
                           ws, q, W, temp, node_outp, B);

    hipLaunchKernelGGL(k3_combine, dim3(4), dim3(256), 0, stream,
                       node_outp, local_outp, n_nodes, out);
}